// Round 1
// baseline (76.445 us; speedup 1.0000x reference)
//
#include <hip/hip_runtime.h>
#include <math.h>

// Problem constants (from reference)
#define D 1024      // INPUT_SIZE
#define M 4096      // OUT_H * OUT_W
#define B 64        // BATCH
#define SOM_EPS 1e-6

// ---------------------------------------------------------------------------
// Kernel 1: per-row moments of weight [D, M] (row-major, row d contiguous).
//   S1[d] = sum_m w[d,m]
//   S2[d] = sum_m w[d,m]^2
// Accumulated in double so the later argmin matches the exact-math argmin
// (the np reference is high precision; a flipped argmin costs up to ~63 in
// the location output vs threshold 1.245).
// One block per d; 256 threads; coalesced float4 loads (thread t reads
// float4 index t + k*256).
// ---------------------------------------------------------------------------
__global__ __launch_bounds__(256) void som_stats(const float* __restrict__ w,
                                                 double* __restrict__ S1,
                                                 double* __restrict__ S2) {
    const int d = blockIdx.x;
    const int t = threadIdx.x;
    const float4* row = (const float4*)(w + (size_t)d * M);

    double a1 = 0.0, a2 = 0.0;
#pragma unroll
    for (int k = 0; k < (M / 4) / 256; ++k) {   // 4 iterations
        float4 v = row[t + k * 256];
        a1 += (double)v.x + (double)v.y + (double)v.z + (double)v.w;
        a2 += (double)v.x * (double)v.x + (double)v.y * (double)v.y
            + (double)v.z * (double)v.z + (double)v.w * (double)v.w;
    }

    // wave (64-lane) reduction
    for (int off = 32; off > 0; off >>= 1) {
        a1 += __shfl_down(a1, off);
        a2 += __shfl_down(a2, off);
    }

    __shared__ double l1[4], l2[4];
    const int wave = t >> 6, lane = t & 63;
    if (lane == 0) { l1[wave] = a1; l2[wave] = a2; }
    __syncthreads();
    if (t == 0) {
        S1[d] = l1[0] + l1[1] + l1[2] + l1[3];
        S2[d] = l2[0] + l2[1] + l2[2] + l2[3];
    }
}

// ---------------------------------------------------------------------------
// Kernel 2: per batch b, over d in [0,1024):
//   dist2[d] = M*s^2 - 2*s*S1[d] + S2[d],  s = x[b,d] + eps   (double)
// min+argmin over d (first-index tie-break, matching jnp.argmin), then:
//   out[2b], out[2b+1] = locations[argmin]
//   loss_ws[b]         = sqrt(min dist2)
// One block per b, 1024 threads (thread = d).
// ---------------------------------------------------------------------------
__global__ __launch_bounds__(1024) void som_argmin(const float* __restrict__ x,
                                                   const double* __restrict__ S1,
                                                   const double* __restrict__ S2,
                                                   const float* __restrict__ loc,
                                                   float* __restrict__ out,
                                                   double* __restrict__ loss_ws) {
    const int b = blockIdx.x;
    const int d = threadIdx.x;

    double s = (double)x[b * D + d] + SOM_EPS;
    double v = (double)M * s * s - 2.0 * s * S1[d] + S2[d];
    int idx = d;

    // wave (64-lane) argmin; shfl_down pulls higher-d candidates downward,
    // tie-break keeps the lower index (first occurrence).
    for (int off = 32; off > 0; off >>= 1) {
        double ov = __shfl_down(v, off);
        int    oi = __shfl_down(idx, off);
        if (ov < v || (ov == v && oi < idx)) { v = ov; idx = oi; }
    }

    __shared__ double lv[16];
    __shared__ int    li[16];
    const int wave = d >> 6, lane = d & 63;
    if (lane == 0) { lv[wave] = v; li[wave] = idx; }
    __syncthreads();

    if (d == 0) {
        double bv = lv[0]; int bi = li[0];
#pragma unroll
        for (int wv = 1; wv < 16; ++wv) {
            if (lv[wv] < bv || (lv[wv] == bv && li[wv] < bi)) { bv = lv[wv]; bi = li[wv]; }
        }
        out[2 * b]     = loc[2 * bi];
        out[2 * b + 1] = loc[2 * bi + 1];
        loss_ws[b]     = sqrt(bv);
    }
}

// ---------------------------------------------------------------------------
// Kernel 3: loss = sum_b loss_ws[b] / B  ->  out[2*B] (out index 128)
// One wave of 64 threads.
// ---------------------------------------------------------------------------
__global__ __launch_bounds__(64) void som_loss(const double* __restrict__ loss_ws,
                                               float* __restrict__ out) {
    double v = loss_ws[threadIdx.x];
    for (int off = 32; off > 0; off >>= 1) v += __shfl_down(v, off);
    if (threadIdx.x == 0) out[2 * B] = (float)(v / (double)B);
}

extern "C" void kernel_launch(void* const* d_in, const int* in_sizes, int n_in,
                              void* d_out, int out_size, void* d_ws, size_t ws_size,
                              hipStream_t stream) {
    const float* x   = (const float*)d_in[0];   // [B, D]
    const float* w   = (const float*)d_in[1];   // [D, M]
    const float* loc = (const float*)d_in[2];   // [M, 2]
    float* out = (float*)d_out;                 // [B*2 locations, then 1 loss]

    // workspace layout (doubles): S1[0:D), S2[D:2D), loss_ws[2D:2D+B)
    double* ws_d    = (double*)d_ws;
    double* S1      = ws_d;
    double* S2      = ws_d + D;
    double* loss_ws = ws_d + 2 * D;

    som_stats <<<D, 256, 0, stream>>>(w, S1, S2);
    som_argmin<<<B, 1024, 0, stream>>>(x, S1, S2, loc, out, loss_ws);
    som_loss  <<<1, 64, 0, stream>>>(loss_ws, out);
}